// Round 7
// baseline (1011.940 us; speedup 1.0000x reference)
//
#include <hip/hip_runtime.h>

#define N 128
#define NITER 60
#define PST 132      // partial stride (floats): mult of 4 -> 16B-aligned rows for b128
#define COLOFF 2128  // colpart base within a group buffer: %32==16 (bank half shift)
#define GBUF (COLOFF + 16 * PST)   // 4240 floats per group

typedef float v2f __attribute__((ext_vector_type(2)));
typedef float v4f __attribute__((ext_vector_type(4)));

// Anti-phase wave-group stagger. One 512-thread block = two 256-thread groups,
// each owning ONE batch row with r4's exact per-thread state (64 z + 64 w).
// Roles alternate per barrier window: group g updates while group 1-g reduces.
// Every window contains a dense ~1000-cyc update on every SIMD (2 waves/SIMD:
// one updating, one reducing), so reduce reads + y-write + barrier hide under
// the other group's update BY CONSTRUCTION (r4's 2 independent blocks phase-
// locked instead: VALUBusy stuck at 60-64% across r0/r4/r6 while wall tracked
// instr-count/0.63). 1 barrier per row-iter (r4: 2). Per-row math, publish
// layout, reduce order bitwise-identical to r4. r6 lesson: occupancy is NOT
// the lever (2x occ, same 63% busy); instruction count + phase overlap is.
__global__ __launch_bounds__(512, 2)
void gfusedmax_kernel(const float* __restrict__ x,
                      const float* __restrict__ A,
                      float* __restrict__ out)
{
    const int tid = threadIdx.x;
    const int grp = tid >> 8;          // wave-uniform: waves 0-3 = grp0, 4-7 = grp1
    const int lt  = tid & 255;
    const int tr  = lt >> 4;           // 0..15
    const int tc  = lt & 15;           // 0..15
    const int i0  = tr * 8;
    const int j0  = tc * 8;
    const int row = blockIdx.x * 2 + grp;

    __shared__ __align__(16) float parts[2][GBUF];   // per-group rowpart@0, colpart@COLOFF
    __shared__ __align__(16) float yv[2][N];
    __shared__ float sorted[2][N];
    __shared__ float red[2][8];

    const float step = 1.0f / 256.0f;  // 1/(2N), exact power of two

    // ---- load w = lam*A (lam=1) tile for this group's row, init z=0 ----
    v2f w2[8][4];
    v2f z2[8][4];
    const float* Ab = A + (size_t)row * N * N;
    #pragma unroll
    for (int r = 0; r < 8; ++r) {
        const v4f* src = (const v4f*)(Ab + (size_t)(i0 + r) * N + j0);
        v4f p0 = src[0];
        v4f p1 = src[1];
        w2[r][0] = p0.lo; w2[r][1] = p0.hi;
        w2[r][2] = p1.lo; w2[r][3] = p1.hi;
        #pragma unroll
        for (int cp = 0; cp < 4; ++cp) z2[r][cp] = (v2f)0.0f;
    }

    // reduce pairing: lanes (2m, 2m+1) compute y[m]; even=rowsum, odd=colsum
    const int m = lt >> 1;
    const float xm = x[(size_t)row * N + m];
    const float* pb = &parts[grp][0] + ((lt & 1) ? COLOFF : 0);
    float* yvg = yv[grp];

    // seed y = step*x (iteration-0 partials are zero)
    if (lt < N) yvg[lt] = step * x[(size_t)row * N + lt];
    __syncthreads();

    // ---- role bodies ----
    auto UPDATE = [&]() {
        // read y broadcast
        v2f drs[8], ec2[4];
        #pragma unroll
        for (int r = 0; r < 8; ++r) drs[r] = (v2f)yvg[i0 + r];
        v4f e0 = *(const v4f*)&yvg[j0];
        v4f e1 = *(const v4f*)&yvg[j0 + 4];
        ec2[0] = e0.lo; ec2[1] = e0.hi;
        ec2[2] = e1.lo; ec2[3] = e1.hi;
        v2f pr2[8], pc2[4];
        #pragma unroll
        for (int r = 0; r < 8; ++r) {
            #pragma unroll
            for (int cp = 0; cp < 4; ++cp) {
                v2f t  = (z2[r][cp] + drs[r]) - ec2[cp];
                v2f wv = w2[r][cp];
                v2f zn;
                zn.x = __builtin_amdgcn_fmed3f(t.x, -wv.x, wv.x);
                zn.y = __builtin_amdgcn_fmed3f(t.y, -wv.y, wv.y);
                z2[r][cp] = zn;
                pr2[r]  = (cp == 0) ? zn : pr2[r] + zn;
                pc2[cp] = (r == 0)  ? zn : pc2[cp] + zn;
            }
        }
        // publish partials (r4's b128 layout, same values as publish-at-head)
        v4f r0, r1, c0, c1;
        r0.x = pr2[0].x + pr2[0].y;  r0.y = pr2[1].x + pr2[1].y;
        r0.z = pr2[2].x + pr2[2].y;  r0.w = pr2[3].x + pr2[3].y;
        r1.x = pr2[4].x + pr2[4].y;  r1.y = pr2[5].x + pr2[5].y;
        r1.z = pr2[6].x + pr2[6].y;  r1.w = pr2[7].x + pr2[7].y;
        c0.x = pc2[0].x; c0.y = pc2[0].y; c0.z = pc2[1].x; c0.w = pc2[1].y;
        c1.x = pc2[2].x; c1.y = pc2[2].y; c1.z = pc2[3].x; c1.w = pc2[3].y;
        *(v4f*)&parts[grp][tc * PST + i0]              = r0;
        *(v4f*)&parts[grp][tc * PST + i0 + 4]          = r1;
        *(v4f*)&parts[grp][COLOFF + tr * PST + j0]     = c0;
        *(v4f*)&parts[grp][COLOFF + tr * PST + j0 + 4] = c1;
    };

    auto REDUCE = [&](bool raw) {
        // lanes (2m,2m+1): even sums rowparts, odd colparts (same k order as r4)
        float acc = 0.0f;
        #pragma unroll
        for (int k = 0; k < 16; ++k) acc += pb[k * PST + m];
        float other = __shfl_xor(acc, 1, 64);
        if (!(lt & 1)) {
            float y = (xm - acc) + other;      // (x - rowsum) + colsum
            // 2^-8 scaling exact: step*yi - step*yj == step*(yi - yj)
            yvg[m] = raw ? y : step * y;
        }
    };

    // ---- staggered main loop: per round, window A then window B ----
    for (int t = 0; t <= NITER; ++t) {
        // window A: grp0 update #t+1 (t<60); grp1 reduce (raw at t==60)
        if (grp == 0) { if (t < NITER) UPDATE(); }
        else          { if (t > 0) REDUCE(t == NITER); }
        __syncthreads();
        if (t == NITER) break;
        // window B: grp1 update #t+1; grp0 reduce (raw at t==59, after update #60)
        if (grp == 1) UPDATE();
        else          REDUCE(t == NITER - 1);
        __syncthreads();
    }
    // both yv[] hold raw final y now

    // ---- sparsemax per group (concurrent; barrier counts match across groups) ----
    float* sog = sorted[grp];
    float v = 0.0f;
    if (lt < N) {
        v = yvg[lt];
        int rk = 0;
        for (int k = 0; k < N; ++k) {
            float u = yvg[k];
            rk += (u > v) || (u == v && k < lt);
        }
        sog[rk] = v;   // rank is a permutation (ties broken by index)
    }
    __syncthreads();

    float s = 0.0f, csum = 0.0f;
    if (lt < N) {
        s = sog[lt];
        for (int mm = 0; mm < N; ++mm) {       // uniform index -> LDS broadcast
            float u = sog[mm];
            if (mm <= lt) csum += u;           // inclusive prefix at sorted pos
        }
    }
    bool maskb = (lt < N) && (1.0f + (float)(lt + 1) * s > csum);
    float aRed = maskb ? s : 0.0f;
    float bRed = maskb ? 1.0f : 0.0f;
    #pragma unroll
    for (int off = 32; off >= 1; off >>= 1) {
        aRed += __shfl_down(aRed, off, 64);
        bRed += __shfl_down(bRed, off, 64);
    }
    const int wid = lt >> 6;   // 0..3 within group
    if ((lt & 63) == 0) { red[grp][wid * 2] = aRed; red[grp][wid * 2 + 1] = bRed; }
    __syncthreads();
    const float tau = (red[grp][0] + red[grp][2] + red[grp][4] + red[grp][6] - 1.0f)
                    / (red[grp][1] + red[grp][3] + red[grp][5] + red[grp][7]);
    if (lt < N) out[(size_t)row * N + lt] = fmaxf(v - tau, 0.0f);
}

extern "C" void kernel_launch(void* const* d_in, const int* in_sizes, int n_in,
                              void* d_out, int out_size, void* d_ws, size_t ws_size,
                              hipStream_t stream) {
    const float* x = (const float*)d_in[0];
    const float* A = (const float*)d_in[1];
    float* out = (float*)d_out;
    const int B = in_sizes[0] / N;   // 4096 rows
    gfusedmax_kernel<<<B / 2, 512, 0, stream>>>(x, A, out);
}